// Round 1
// baseline (466.725 us; speedup 1.0000x reference)
//
#include <hip/hip_runtime.h>

#define EPSF 1e-6f

typedef __bf16 bf16x8 __attribute__((ext_vector_type(8)));
typedef float f32x4 __attribute__((ext_vector_type(4)));

__device__ __forceinline__ unsigned short f2bf(float f) {
  unsigned int u = __builtin_bit_cast(unsigned int, f);
  u += 0x7fffu + ((u >> 16) & 1u);
  return (unsigned short)(u >> 16);
}

// ---------------- log_map at origin: x [2048,1024] -> v (bf16) ----------------
__global__ __launch_bounds__(256) void prep_logmap(
    const float* __restrict__ x, unsigned short* __restrict__ vbf) {
  int row = blockIdx.x;  // 0..2047
  int tid = threadIdx.x;
  const float* xr = x + (size_t)row * 1024;
  float vals[4];
  float ssq = 0.f;
#pragma unroll
  for (int i = 0; i < 4; ++i) {
    int c = tid + i * 256;
    float t = xr[c];
    if (c == 0) {
      vals[i] = 0.f;
    } else {
      t = fminf(fmaxf(t, -8.f), 8.f);
      vals[i] = t;
      ssq += t * t;
    }
  }
#pragma unroll
  for (int off = 32; off; off >>= 1) ssq += __shfl_xor(ssq, off);
  __shared__ float red[4];
  int wv = tid >> 6;
  if ((tid & 63) == 0) red[wv] = ssq;
  __syncthreads();
  ssq = red[0] + red[1] + red[2] + red[3];

  float y0 = sqrtf(1.f + ssq + EPSF);
  float xy = fminf(-y0, -(1.f + EPSF));
  float mxy = fmaxf(-xy, 1.f + EPSF);
  float dd = fmaxf(acoshf(mxy), 0.001f);
  float d0 = y0 + xy;                    // direc[0]
  float inn = ssq - d0 * d0;             // Lorentz inner(direc,direc)
  float dn = sqrtf(fmaxf(inn, EPSF));
  float inv = dd / (dn + EPSF);

  unsigned short* vr = vbf + (size_t)row * 1024;
#pragma unroll
  for (int i = 0; i < 4; ++i) {
    int c = tid + i * 256;
    float o = (c == 0) ? d0 * inv : vals[i] * inv;
    vr[c] = f2bf(o);
  }
}

// ---------------- f32 -> bf16 convert (weights) ----------------
__global__ __launch_bounds__(256) void f32_to_bf16(
    const float* __restrict__ src, unsigned short* __restrict__ dst, int n4) {
  int i = blockIdx.x * 256 + threadIdx.x;
  if (i < n4) {
    f32x4 v = ((const f32x4*)src)[i];
    ushort4 o;
    o.x = f2bf(v[0]); o.y = f2bf(v[1]); o.z = f2bf(v[2]); o.w = f2bf(v[3]);
    ((ushort4*)dst)[i] = o;
  }
}

// ---------------- C[M,N] = A[M,K] * Bw[N,K]^T  (bf16 in, f32 out) ----------------
__global__ __launch_bounds__(256) void gemm_bt(
    const unsigned short* __restrict__ A, const unsigned short* __restrict__ Bw,
    float* __restrict__ C, int M, int N, int K) {
  __shared__ unsigned short As[64][72];
  __shared__ unsigned short Bs[64][72];
  int tid = threadIdx.x;
  int lane = tid & 63, wave = tid >> 6;
  int wm = (wave >> 1) * 32, wn = (wave & 1) * 32;
  int row0 = blockIdx.x * 64, col0 = blockIdx.y * 64;
  f32x4 acc[2][2] = {};
  int lr = lane & 15, lk = (lane >> 4) * 8;

  for (int k0 = 0; k0 < K; k0 += 64) {
    __syncthreads();
#pragma unroll
    for (int it = 0; it < 2; ++it) {
      int idx = tid + it * 256;
      int r = idx >> 3, c = (idx & 7) * 8;
      *(uint4*)&As[r][c] = *(const uint4*)&A[(size_t)(row0 + r) * K + k0 + c];
      *(uint4*)&Bs[r][c] = *(const uint4*)&Bw[(size_t)(col0 + r) * K + k0 + c];
    }
    __syncthreads();
#pragma unroll
    for (int kk = 0; kk < 64; kk += 32) {
      bf16x8 a0 = *(const bf16x8*)&As[wm + lr][kk + lk];
      bf16x8 a1 = *(const bf16x8*)&As[wm + 16 + lr][kk + lk];
      bf16x8 b0 = *(const bf16x8*)&Bs[wn + lr][kk + lk];
      bf16x8 b1 = *(const bf16x8*)&Bs[wn + 16 + lr][kk + lk];
      acc[0][0] = __builtin_amdgcn_mfma_f32_16x16x32_bf16(a0, b0, acc[0][0], 0, 0, 0);
      acc[0][1] = __builtin_amdgcn_mfma_f32_16x16x32_bf16(a0, b1, acc[0][1], 0, 0, 0);
      acc[1][0] = __builtin_amdgcn_mfma_f32_16x16x32_bf16(a1, b0, acc[1][0], 0, 0, 0);
      acc[1][1] = __builtin_amdgcn_mfma_f32_16x16x32_bf16(a1, b1, acc[1][1], 0, 0, 0);
    }
  }
  int orow = (lane >> 4) * 4, ocol = lane & 15;
#pragma unroll
  for (int i = 0; i < 2; ++i)
#pragma unroll
    for (int j = 0; j < 2; ++j)
#pragma unroll
      for (int r = 0; r < 4; ++r) {
        int rr = row0 + wm + i * 16 + orow + r;
        int cc = col0 + wn + j * 16 + ocol;
        C[(size_t)rr * N + cc] = acc[i][j][r];
      }
}

// ---------------- per-head projection (clip +/-5, recompute x0) ----------------
// mode 1 (q): write -x0, scale whole row by 0.125 (folds 1/sqrt(dh) into q)
// mode 0 (k): write +x0, scale 1
__global__ __launch_bounds__(256) void proj_heads(float* __restrict__ buf, int qmode) {
  int tid = threadIdx.x;
  int g = blockIdx.x * 4 + (tid >> 6);  // (row*16 + head)
  int lane = tid & 63;
  float* p = buf + (size_t)(g >> 4) * 1024 + (g & 15) * 64;
  float t = p[lane];
  float sp = fminf(fmaxf(t, -5.f), 5.f);
  float ssq = (lane == 0) ? 0.f : sp * sp;
#pragma unroll
  for (int off = 32; off; off >>= 1) ssq += __shfl_xor(ssq, off);
  float x0 = sqrtf(1.f + ssq + EPSF);
  float scale = qmode ? 0.125f : 1.f;
  float o = (lane == 0) ? (qmode ? -x0 : x0) : sp;
  p[lane] = o * scale;
}

// ---------------- flash attention, fp32, BQ=BK=64 ----------------
__global__ __launch_bounds__(256) void attn_fp32(
    const float* __restrict__ Q, const float* __restrict__ K,
    const float* __restrict__ V, unsigned short* __restrict__ Obf) {
  const int T = 1024;
  __shared__ float QPs[64][68];  // Q tile, then reused as P tile
  __shared__ float Ks[64][68];
  __shared__ float Vs[64][68];
  int tid = threadIdx.x;
  int bh = blockIdx.x >> 4;  // / (T/64)
  int qt = blockIdx.x & 15;
  int b = bh >> 4, h = bh & 15;
  size_t base = ((size_t)b * T) * 1024 + (size_t)h * 64;
  const float* Qb = Q + base + (size_t)qt * 64 * 1024;

#pragma unroll
  for (int i = 0; i < 4; ++i) {
    int idx = tid + i * 256;
    int r = idx >> 4, c = (idx & 15) * 4;
    *(f32x4*)&QPs[r][c] = *(const f32x4*)&Qb[(size_t)r * 1024 + c];
  }
  __syncthreads();
  int qi = tid >> 2, jg = tid & 3;
  f32x4 qreg[16];
  {
    const f32x4* qrow = (const f32x4*)&QPs[qi][0];
#pragma unroll
    for (int c4 = 0; c4 < 16; ++c4) qreg[c4] = qrow[c4];
  }
  f32x4 o4[4] = {};
  float m = -1e30f, l = 0.f;

  for (int kt = 0; kt < 16; ++kt) {
    __syncthreads();
    const float* Kb = K + base + (size_t)kt * 64 * 1024;
    const float* Vb = V + base + (size_t)kt * 64 * 1024;
#pragma unroll
    for (int i = 0; i < 4; ++i) {
      int idx = tid + i * 256;
      int r = idx >> 4, c = (idx & 15) * 4;
      *(f32x4*)&Ks[r][c] = *(const f32x4*)&Kb[(size_t)r * 1024 + c];
      *(f32x4*)&Vs[r][c] = *(const f32x4*)&Vb[(size_t)r * 1024 + c];
    }
    __syncthreads();

    float s[16];
#pragma unroll
    for (int jj = 0; jj < 16; ++jj) {
      int j = jg * 16 + jj;
      const f32x4* krow = (const f32x4*)&Ks[j][0];
      f32x4 a = {};
#pragma unroll
      for (int c4 = 0; c4 < 16; ++c4) a += qreg[c4] * krow[c4];
      s[jj] = a[0] + a[1] + a[2] + a[3];
    }
    float tmax = s[0];
#pragma unroll
    for (int jj = 1; jj < 16; ++jj) tmax = fmaxf(tmax, s[jj]);
    tmax = fmaxf(tmax, __shfl_xor(tmax, 1));
    tmax = fmaxf(tmax, __shfl_xor(tmax, 2));
    float nm = fmaxf(m, tmax);
    float sc = __expf(m - nm);
    float ps = 0.f;
#pragma unroll
    for (int jj = 0; jj < 16; ++jj) {
      float p = __expf(s[jj] - nm);
      QPs[qi][jg * 16 + jj] = p;
      ps += p;
    }
    ps += __shfl_xor(ps, 1);
    ps += __shfl_xor(ps, 2);
    l = l * sc + ps;
    m = nm;
#pragma unroll
    for (int c4 = 0; c4 < 4; ++c4) o4[c4] = o4[c4] * sc;
    __syncthreads();
#pragma unroll 4
    for (int j = 0; j < 64; ++j) {
      float p = QPs[qi][j];
      const f32x4* vrow = (const f32x4*)&Vs[j][0];
#pragma unroll
      for (int c4 = 0; c4 < 4; ++c4) o4[c4] += p * vrow[jg * 4 + c4];
    }
  }
  float invl = 1.f / l;
  unsigned short* orow = Obf + base + (size_t)(qt * 64 + qi) * 1024 + jg * 16;
#pragma unroll
  for (int c4 = 0; c4 < 4; ++c4)
#pragma unroll
    for (int e = 0; e < 4; ++e) orow[c4 * 4 + e] = f2bf(o4[c4][e] * invl);
}

// ---------------- exp_map at origin + project ----------------
__global__ __launch_bounds__(256) void expmap_project(
    const float* __restrict__ c2, float* __restrict__ out) {
  int row = blockIdx.x;
  int tid = threadIdx.x;
  const float* cr = c2 + (size_t)row * 1024;
  float vals[4];
  float ssq = 0.f;
#pragma unroll
  for (int i = 0; i < 4; ++i) {
    int c = tid + i * 256;
    float t = cr[c];
    vals[i] = (c == 0) ? 0.f : t;
    ssq += vals[i] * vals[i];
  }
#pragma unroll
  for (int off = 32; off; off >>= 1) ssq += __shfl_xor(ssq, off);
  __shared__ float red1[4], red2[4];
  int wv = tid >> 6;
  if ((tid & 63) == 0) red1[wv] = ssq;
  __syncthreads();
  ssq = red1[0] + red1[1] + red1[2] + red1[3];
  float vn = fminf(sqrtf(ssq + EPSF), 5.f);
  float bf = sinhf(vn) / (vn + EPSF);
  float s2 = 0.f;
#pragma unroll
  for (int i = 0; i < 4; ++i) {
    float r = fminf(fmaxf(bf * vals[i], -8.f), 8.f);
    vals[i] = r;
    s2 += r * r;
  }
#pragma unroll
  for (int off = 32; off; off >>= 1) s2 += __shfl_xor(s2, off);
  if ((tid & 63) == 0) red2[wv] = s2;
  __syncthreads();
  s2 = red2[0] + red2[1] + red2[2] + red2[3];
  float x0 = sqrtf(1.f + s2 + EPSF);
  float* orow = out + (size_t)row * 1024;
#pragma unroll
  for (int i = 0; i < 4; ++i) {
    int c = tid + i * 256;
    orow[c] = (c == 0) ? x0 : vals[i];
  }
}

extern "C" void kernel_launch(void* const* d_in, const int* in_sizes, int n_in,
                              void* d_out, int out_size, void* d_ws, size_t ws_size,
                              hipStream_t stream) {
  (void)in_sizes; (void)n_in; (void)out_size; (void)ws_size;
  const float* x  = (const float*)d_in[0];
  const float* Wq = (const float*)d_in[1];
  const float* Wk = (const float*)d_in[2];
  const float* Wv = (const float*)d_in[3];
  const float* Wo = (const float*)d_in[4];
  float* out = (float*)d_out;

  char* w = (char*)d_ws;
  unsigned short* vbf = (unsigned short*)w; w += (size_t)2048 * 1024 * 2;
  unsigned short* wqb = (unsigned short*)w; w += (size_t)1024 * 1024 * 2;
  unsigned short* wkb = (unsigned short*)w; w += (size_t)1024 * 1024 * 2;
  unsigned short* wvb = (unsigned short*)w; w += (size_t)1024 * 1024 * 2;
  unsigned short* wob = (unsigned short*)w; w += (size_t)1024 * 1024 * 2;
  float* qf  = (float*)w; w += (size_t)2048 * 1024 * 4;
  float* kf  = (float*)w; w += (size_t)2048 * 1024 * 4;
  float* vvf = (float*)w; w += (size_t)2048 * 1024 * 4;
  unsigned short* aob = (unsigned short*)w; w += (size_t)2048 * 1024 * 2;
  float* c2 = (float*)w;  w += (size_t)2048 * 1024 * 4;

  prep_logmap<<<2048, 256, 0, stream>>>(x, vbf);
  f32_to_bf16<<<1024, 256, 0, stream>>>(Wq, wqb, 262144);
  f32_to_bf16<<<1024, 256, 0, stream>>>(Wk, wkb, 262144);
  f32_to_bf16<<<1024, 256, 0, stream>>>(Wv, wvb, 262144);
  f32_to_bf16<<<1024, 256, 0, stream>>>(Wo, wob, 262144);

  dim3 g(32, 16);
  gemm_bt<<<g, 256, 0, stream>>>(vbf, wqb, qf, 2048, 1024, 1024);
  gemm_bt<<<g, 256, 0, stream>>>(vbf, wkb, kf, 2048, 1024, 1024);
  gemm_bt<<<g, 256, 0, stream>>>(vbf, wvb, vvf, 2048, 1024, 1024);

  proj_heads<<<8192, 256, 0, stream>>>(qf, 1);
  proj_heads<<<8192, 256, 0, stream>>>(kf, 0);

  attn_fp32<<<512, 256, 0, stream>>>(qf, kf, vvf, aob);

  gemm_bt<<<g, 256, 0, stream>>>(aob, wob, c2, 2048, 1024, 1024);
  expmap_project<<<2048, 256, 0, stream>>>(c2, out);
}

// Round 2
// 161.396 us; speedup vs baseline: 2.8918x; 2.8918x over previous
//
#include <hip/hip_runtime.h>

#define EPSF 1e-6f

typedef __bf16 bf16x8 __attribute__((ext_vector_type(8)));
typedef float f32x4 __attribute__((ext_vector_type(4)));

__device__ __forceinline__ unsigned short f2bf(float f) {
  unsigned int u = __builtin_bit_cast(unsigned int, f);
  u += 0x7fffu + ((u >> 16) & 1u);
  return (unsigned short)(u >> 16);
}

// ---------------- log_map at origin: x [2048,1024] -> v (bf16) ----------------
__global__ __launch_bounds__(256) void prep_logmap(
    const float* __restrict__ x, unsigned short* __restrict__ vbf) {
  int row = blockIdx.x;
  int tid = threadIdx.x;
  const float* xr = x + (size_t)row * 1024;
  float vals[4];
  float ssq = 0.f;
#pragma unroll
  for (int i = 0; i < 4; ++i) {
    int c = tid + i * 256;
    float t = xr[c];
    if (c == 0) {
      vals[i] = 0.f;
    } else {
      t = fminf(fmaxf(t, -8.f), 8.f);
      vals[i] = t;
      ssq += t * t;
    }
  }
#pragma unroll
  for (int off = 32; off; off >>= 1) ssq += __shfl_xor(ssq, off);
  __shared__ float red[4];
  int wv = tid >> 6;
  if ((tid & 63) == 0) red[wv] = ssq;
  __syncthreads();
  ssq = red[0] + red[1] + red[2] + red[3];

  float y0 = sqrtf(1.f + ssq + EPSF);
  float xy = fminf(-y0, -(1.f + EPSF));
  float mxy = fmaxf(-xy, 1.f + EPSF);
  float dd = fmaxf(acoshf(mxy), 0.001f);
  float d0 = y0 + xy;
  float inn = ssq - d0 * d0;
  float dn = sqrtf(fmaxf(inn, EPSF));
  float inv = dd / (dn + EPSF);

  unsigned short* vr = vbf + (size_t)row * 1024;
#pragma unroll
  for (int i = 0; i < 4; ++i) {
    int c = tid + i * 256;
    float o = (c == 0) ? d0 * inv : vals[i] * inv;
    vr[c] = f2bf(o);
  }
}

// ---------------- f32 -> bf16 convert (weights) ----------------
__global__ __launch_bounds__(256) void f32_to_bf16(
    const float* __restrict__ src, unsigned short* __restrict__ dst, int n4) {
  int i = blockIdx.x * 256 + threadIdx.x;
  if (i < n4) {
    f32x4 v = ((const f32x4*)src)[i];
    ushort4 o;
    o.x = f2bf(v[0]); o.y = f2bf(v[1]); o.z = f2bf(v[2]); o.w = f2bf(v[3]);
    ((ushort4*)dst)[i] = o;
  }
}

// ---------------- C[M,N] = A[M,K] * Bw[N,K]^T  (bf16 in; f32 or bf16 out) ----------------
template <bool BF16OUT>
__global__ __launch_bounds__(256) void gemm_bt(
    const unsigned short* __restrict__ A, const unsigned short* __restrict__ Bw,
    void* __restrict__ Cv, int M, int N, int K) {
  __shared__ unsigned short As[64][72];
  __shared__ unsigned short Bs[64][72];
  int tid = threadIdx.x;
  int lane = tid & 63, wave = tid >> 6;
  int wm = (wave >> 1) * 32, wn = (wave & 1) * 32;
  int row0 = blockIdx.x * 64, col0 = blockIdx.y * 64;
  f32x4 acc[2][2] = {};
  int lr = lane & 15, lk = (lane >> 4) * 8;

  for (int k0 = 0; k0 < K; k0 += 64) {
    __syncthreads();
#pragma unroll
    for (int it = 0; it < 2; ++it) {
      int idx = tid + it * 256;
      int r = idx >> 3, c = (idx & 7) * 8;
      *(uint4*)&As[r][c] = *(const uint4*)&A[(size_t)(row0 + r) * K + k0 + c];
      *(uint4*)&Bs[r][c] = *(const uint4*)&Bw[(size_t)(col0 + r) * K + k0 + c];
    }
    __syncthreads();
#pragma unroll
    for (int kk = 0; kk < 64; kk += 32) {
      bf16x8 a0 = *(const bf16x8*)&As[wm + lr][kk + lk];
      bf16x8 a1 = *(const bf16x8*)&As[wm + 16 + lr][kk + lk];
      bf16x8 b0 = *(const bf16x8*)&Bs[wn + lr][kk + lk];
      bf16x8 b1 = *(const bf16x8*)&Bs[wn + 16 + lr][kk + lk];
      acc[0][0] = __builtin_amdgcn_mfma_f32_16x16x32_bf16(a0, b0, acc[0][0], 0, 0, 0);
      acc[0][1] = __builtin_amdgcn_mfma_f32_16x16x32_bf16(a0, b1, acc[0][1], 0, 0, 0);
      acc[1][0] = __builtin_amdgcn_mfma_f32_16x16x32_bf16(a1, b0, acc[1][0], 0, 0, 0);
      acc[1][1] = __builtin_amdgcn_mfma_f32_16x16x32_bf16(a1, b1, acc[1][1], 0, 0, 0);
    }
  }
  int orow = (lane >> 4) * 4, ocol = lane & 15;
#pragma unroll
  for (int i = 0; i < 2; ++i)
#pragma unroll
    for (int j = 0; j < 2; ++j)
#pragma unroll
      for (int r = 0; r < 4; ++r) {
        int rr = row0 + wm + i * 16 + orow + r;
        int cc = col0 + wn + j * 16 + ocol;
        if (BF16OUT)
          ((unsigned short*)Cv)[(size_t)rr * N + cc] = f2bf(acc[i][j][r]);
        else
          ((float*)Cv)[(size_t)rr * N + cc] = acc[i][j][r];
      }
}

// ---------------- per-head projection -> bf16 ----------------
// qmode=1: write -x0 at d=0, scale row by 0.125 (folds sign + 1/sqrt(dh) into q)
__global__ __launch_bounds__(256) void proj_heads_bf16(
    const float* __restrict__ src, unsigned short* __restrict__ dst, int qmode) {
  int tid = threadIdx.x;
  int g = blockIdx.x * 4 + (tid >> 6);  // row*16 + head
  int lane = tid & 63;
  size_t off = (size_t)(g >> 4) * 1024 + (g & 15) * 64 + lane;
  float t = src[off];
  float sp = fminf(fmaxf(t, -5.f), 5.f);
  float ssq = (lane == 0) ? 0.f : sp * sp;
#pragma unroll
  for (int o = 32; o; o >>= 1) ssq += __shfl_xor(ssq, o);
  float x0 = sqrtf(1.f + ssq + EPSF);
  float o = (lane == 0) ? (qmode ? -x0 : x0) : sp;
  if (qmode) o *= 0.125f;
  dst[off] = f2bf(o);
}

// ---------------- MFMA flash attention ----------------
// Qb,Kb: bf16 [2048][1024] (head-blocked cols); Vtb: bf16 [1024][2048] = V^T per head.
// 4 waves/block; wave w owns 16 q-rows. KV tile = 64.
__global__ __launch_bounds__(256) void attn_mfma(
    const unsigned short* __restrict__ Qb, const unsigned short* __restrict__ Kb,
    const unsigned short* __restrict__ Vtb, unsigned short* __restrict__ Obf) {
  __shared__ unsigned short Ks[64 * 64];
  __shared__ unsigned short Vs[64 * 64];
  __shared__ unsigned short Ps[4 * 16 * 64];
  int tid = threadIdx.x;
  int lane = tid & 63, w = tid >> 6;
  int g = lane >> 4, lq = lane & 15;
  int bh = blockIdx.x >> 4, qt = blockIdx.x & 15;
  int b = bh >> 4, h = bh & 15;

  // hoisted Q B-fragments (q = w*16 + lq)
  const unsigned short* qrow =
      Qb + (size_t)(b * 1024 + qt * 64 + w * 16 + lq) * 1024 + h * 64;
  bf16x8 qf0 = *(const bf16x8*)(qrow + g * 8);
  bf16x8 qf1 = *(const bf16x8*)(qrow + 32 + g * 8);

  float mreg = -1e30f, lreg = 0.f;
  f32x4 acc[4] = {};
  unsigned short* Pw = Ps + w * 16 * 64;
  int sx = 8 * (lq & 7);  // read-side swizzle for rows == lq (mod 8)

  const unsigned short* Ksrc = Kb + (size_t)(b * 1024) * 1024 + h * 64;
  const unsigned short* Vsrc = Vtb + (size_t)(h * 64) * 2048 + b * 1024;

  for (int kt = 0; kt < 16; ++kt) {
    __syncthreads();
#pragma unroll
    for (int it = 0; it < 2; ++it) {
      int i = tid + it * 256;
      int r = i >> 3, c = i & 7;
      uint4 kd = *(const uint4*)(Ksrc + (size_t)(kt * 64 + r) * 1024 + c * 8);
      uint4 vd = *(const uint4*)(Vsrc + (size_t)r * 2048 + kt * 64 + c * 8);
      int sw = r * 64 + 8 * (c ^ (r & 7));
      *(uint4*)&Ks[sw] = kd;
      *(uint4*)&Vs[sw] = vd;
    }
    __syncthreads();

    // S^T[64k x 16q] = K_tile * Q^T : A-frag rows = k, B-frag = q
    f32x4 st[4];
#pragma unroll
    for (int i = 0; i < 4; ++i) {
      int ro = i * 16 + lq;
      int rb = ro * 64, x = 8 * (ro & 7);
      bf16x8 a0 = *(const bf16x8*)&Ks[rb + ((g * 8) ^ x)];
      bf16x8 a1 = *(const bf16x8*)&Ks[rb + ((32 + g * 8) ^ x)];
      f32x4 z = {};
      z = __builtin_amdgcn_mfma_f32_16x16x32_bf16(a0, qf0, z, 0, 0, 0);
      st[i] = __builtin_amdgcn_mfma_f32_16x16x32_bf16(a1, qf1, z, 0, 0, 0);
    }

    // online softmax: lane owns q = w*16+lq, 16 scores (k = i*16 + g*4 + r)
    float pmax = st[0][0];
#pragma unroll
    for (int i = 0; i < 4; ++i)
#pragma unroll
      for (int r = 0; r < 4; ++r) pmax = fmaxf(pmax, st[i][r]);
    pmax = fmaxf(pmax, __shfl_xor(pmax, 16));
    pmax = fmaxf(pmax, __shfl_xor(pmax, 32));
    float nm = fmaxf(mreg, pmax);
    float sc = __expf(mreg - nm);
    mreg = nm;
    float ps = 0.f;
#pragma unroll
    for (int i = 0; i < 4; ++i) {
      ushort4 pq;
      float p0 = __expf(st[i][0] - nm);
      float p1 = __expf(st[i][1] - nm);
      float p2 = __expf(st[i][2] - nm);
      float p3 = __expf(st[i][3] - nm);
      ps += (p0 + p1) + (p2 + p3);
      pq.x = f2bf(p0); pq.y = f2bf(p1); pq.z = f2bf(p2); pq.w = f2bf(p3);
      *(ushort4*)&Pw[lq * 64 + ((g * 4 + i * 16) ^ sx)] = pq;
    }
    ps += __shfl_xor(ps, 16);
    ps += __shfl_xor(ps, 32);
    lreg = lreg * sc + ps;

    float scr[4];
#pragma unroll
    for (int r = 0; r < 4; ++r) scr[r] = __shfl(sc, g * 4 + r);
#pragma unroll
    for (int j = 0; j < 4; ++j)
#pragma unroll
      for (int r = 0; r < 4; ++r) acc[j][r] *= scr[r];

    // PV: A = P[16q x 64k], B = Vt rows d; out D rows = q (g*4+r), cols d = 16j+lq
#pragma unroll
    for (int ks = 0; ks < 2; ++ks) {
      bf16x8 pa = *(const bf16x8*)&Pw[lq * 64 + ((ks * 32 + g * 8) ^ sx)];
#pragma unroll
      for (int j = 0; j < 4; ++j) {
        int vr = 16 * j + lq;
        bf16x8 vb = *(const bf16x8*)&Vs[vr * 64 + ((ks * 32 + g * 8) ^ sx)];
        acc[j] = __builtin_amdgcn_mfma_f32_16x16x32_bf16(pa, vb, acc[j], 0, 0, 0);
      }
    }
  }

  float linv = 1.f / lreg;
  float ilr[4];
#pragma unroll
  for (int r = 0; r < 4; ++r) ilr[r] = __shfl(linv, g * 4 + r);
  unsigned short* obase =
      Obf + (size_t)(b * 1024 + qt * 64 + w * 16) * 1024 + h * 64;
#pragma unroll
  for (int r = 0; r < 4; ++r)
#pragma unroll
    for (int j = 0; j < 4; ++j)
      obase[(size_t)(g * 4 + r) * 1024 + 16 * j + lq] = f2bf(acc[j][r] * ilr[r]);
}

// ---------------- exp_map at origin + project ----------------
__global__ __launch_bounds__(256) void expmap_project(
    const float* __restrict__ c2, float* __restrict__ out) {
  int row = blockIdx.x;
  int tid = threadIdx.x;
  const float* cr = c2 + (size_t)row * 1024;
  float vals[4];
  float ssq = 0.f;
#pragma unroll
  for (int i = 0; i < 4; ++i) {
    int c = tid + i * 256;
    float t = cr[c];
    vals[i] = (c == 0) ? 0.f : t;
    ssq += vals[i] * vals[i];
  }
#pragma unroll
  for (int off = 32; off; off >>= 1) ssq += __shfl_xor(ssq, off);
  __shared__ float red1[4], red2[4];
  int wv = tid >> 6;
  if ((tid & 63) == 0) red1[wv] = ssq;
  __syncthreads();
  ssq = red1[0] + red1[1] + red1[2] + red1[3];
  float vn = fminf(sqrtf(ssq + EPSF), 5.f);
  float bf = sinhf(vn) / (vn + EPSF);
  float s2 = 0.f;
#pragma unroll
  for (int i = 0; i < 4; ++i) {
    float r = fminf(fmaxf(bf * vals[i], -8.f), 8.f);
    vals[i] = r;
    s2 += r * r;
  }
#pragma unroll
  for (int off = 32; off; off >>= 1) s2 += __shfl_xor(s2, off);
  if ((tid & 63) == 0) red2[wv] = s2;
  __syncthreads();
  s2 = red2[0] + red2[1] + red2[2] + red2[3];
  float x0 = sqrtf(1.f + s2 + EPSF);
  float* orow = out + (size_t)row * 1024;
#pragma unroll
  for (int i = 0; i < 4; ++i) {
    int c = tid + i * 256;
    orow[c] = (c == 0) ? x0 : vals[i];
  }
}

extern "C" void kernel_launch(void* const* d_in, const int* in_sizes, int n_in,
                              void* d_out, int out_size, void* d_ws, size_t ws_size,
                              hipStream_t stream) {
  (void)in_sizes; (void)n_in; (void)out_size; (void)ws_size;
  const float* x  = (const float*)d_in[0];
  const float* Wq = (const float*)d_in[1];
  const float* Wk = (const float*)d_in[2];
  const float* Wv = (const float*)d_in[3];
  const float* Wo = (const float*)d_in[4];
  float* out = (float*)d_out;

  char* w = (char*)d_ws;
  unsigned short* vbf = (unsigned short*)w; w += (size_t)2048 * 1024 * 2;  // also qb later
  unsigned short* wqb = (unsigned short*)w; w += (size_t)1024 * 1024 * 2;
  unsigned short* wkb = (unsigned short*)w; w += (size_t)1024 * 1024 * 2;
  unsigned short* wvb = (unsigned short*)w; w += (size_t)1024 * 1024 * 2;
  unsigned short* wob = (unsigned short*)w; w += (size_t)1024 * 1024 * 2;
  float* qf = (float*)w;  w += (size_t)2048 * 1024 * 4;  // also c2 later
  float* kf = (float*)w;  w += (size_t)2048 * 1024 * 4;
  unsigned short* vtb = (unsigned short*)w; w += (size_t)1024 * 2048 * 2;
  unsigned short* kb  = (unsigned short*)w; w += (size_t)2048 * 1024 * 2;
  unsigned short* aob = (unsigned short*)w; w += (size_t)2048 * 1024 * 2;
  unsigned short* qb = vbf;  // reuse: vbf dead after V-gemm
  float* c2 = qf;            // reuse: qf dead after proj_q

  prep_logmap<<<2048, 256, 0, stream>>>(x, vbf);
  f32_to_bf16<<<1024, 256, 0, stream>>>(Wq, wqb, 262144);
  f32_to_bf16<<<1024, 256, 0, stream>>>(Wk, wkb, 262144);
  f32_to_bf16<<<1024, 256, 0, stream>>>(Wv, wvb, 262144);
  f32_to_bf16<<<1024, 256, 0, stream>>>(Wo, wob, 262144);

  dim3 g1(32, 16);
  gemm_bt<false><<<g1, 256, 0, stream>>>(vbf, wqb, qf, 2048, 1024, 1024);
  gemm_bt<false><<<g1, 256, 0, stream>>>(vbf, wkb, kf, 2048, 1024, 1024);
  // V^T = Wv * v^T : A = Wv [1024xK], B-rows = tokens [2048xK] -> C [1024][2048] bf16
  dim3 g2(16, 32);
  gemm_bt<true><<<g2, 256, 0, stream>>>(wvb, vbf, vtb, 1024, 2048, 1024);

  proj_heads_bf16<<<8192, 256, 0, stream>>>(qf, qb, 1);
  proj_heads_bf16<<<8192, 256, 0, stream>>>(kf, kb, 0);

  attn_mfma<<<512, 256, 0, stream>>>(qb, kb, vtb, aob);

  gemm_bt<false><<<g1, 256, 0, stream>>>(aob, wob, c2, 2048, 1024, 1024);
  expmap_project<<<2048, 256, 0, stream>>>(c2, out);
}

// Round 3
// 109.222 us; speedup vs baseline: 4.2732x; 1.4777x over previous
//
#include <hip/hip_runtime.h>

#define EPSF 1e-6f

typedef __bf16 bf16x8 __attribute__((ext_vector_type(8)));
typedef float f32x4 __attribute__((ext_vector_type(4)));
typedef __attribute__((address_space(3))) unsigned int as3_uint;
typedef __attribute__((address_space(1))) const unsigned int as1_uint;

__device__ __forceinline__ unsigned short f2bf(float f) {
  unsigned int u = __builtin_bit_cast(unsigned int, f);
  u += 0x7fffu + ((u >> 16) & 1u);
  return (unsigned short)(u >> 16);
}
__device__ __forceinline__ float bf2f(unsigned short u) {
  unsigned int v = (unsigned int)u << 16;
  return __builtin_bit_cast(float, v);
}

// ---------------- log_map at origin: x [2048,1024] -> v (bf16) ----------------
__global__ __launch_bounds__(256) void prep_logmap(
    const float* __restrict__ x, unsigned short* __restrict__ vbf) {
  int row = blockIdx.x;
  int tid = threadIdx.x;
  const float* xr = x + (size_t)row * 1024;
  float vals[4];
  float ssq = 0.f;
#pragma unroll
  for (int i = 0; i < 4; ++i) {
    int c = tid + i * 256;
    float t = xr[c];
    if (c == 0) {
      vals[i] = 0.f;
    } else {
      t = fminf(fmaxf(t, -8.f), 8.f);
      vals[i] = t;
      ssq += t * t;
    }
  }
#pragma unroll
  for (int off = 32; off; off >>= 1) ssq += __shfl_xor(ssq, off);
  __shared__ float red[4];
  int wv = tid >> 6;
  if ((tid & 63) == 0) red[wv] = ssq;
  __syncthreads();
  ssq = red[0] + red[1] + red[2] + red[3];

  float y0 = sqrtf(1.f + ssq + EPSF);
  float xy = fminf(-y0, -(1.f + EPSF));
  float mxy = fmaxf(-xy, 1.f + EPSF);
  float dd = fmaxf(acoshf(mxy), 0.001f);
  float d0 = y0 + xy;
  float inn = ssq - d0 * d0;
  float dn = sqrtf(fmaxf(inn, EPSF));
  float inv = dd / (dn + EPSF);

  unsigned short* vr = vbf + (size_t)row * 1024;
#pragma unroll
  for (int i = 0; i < 4; ++i) {
    int c = tid + i * 256;
    float o = (c == 0) ? d0 * inv : vals[i] * inv;
    vr[c] = f2bf(o);
  }
}

// ---------------- all 4 weights f32 -> bf16, one dispatch ----------------
__global__ __launch_bounds__(256) void conv_weights(
    const float* __restrict__ Wq, const float* __restrict__ Wk,
    const float* __restrict__ Wv, const float* __restrict__ Wo,
    unsigned short* __restrict__ wqk, unsigned short* __restrict__ wvb,
    unsigned short* __restrict__ wob) {
  int y = blockIdx.y;
  const float* src = (y == 0) ? Wq : (y == 1) ? Wk : (y == 2) ? Wv : Wo;
  unsigned short* dst = (y == 0) ? wqk : (y == 1) ? wqk + 1048576
                        : (y == 2) ? wvb : wob;
  int i = blockIdx.x * 256 + threadIdx.x;  // f32x4 index, 262144 per matrix
  f32x4 v = ((const f32x4*)src)[i];
  ushort4 o;
  o.x = f2bf(v[0]); o.y = f2bf(v[1]); o.z = f2bf(v[2]); o.w = f2bf(v[3]);
  ((ushort4*)dst)[i] = o;
}

// ---------------- C[M,N] = A[M,K] @ Bw[N,K]^T, bf16 in/out ----------------
// BM=128 BN=64 BK=64, 256 threads / 4 waves; wave region 64x32 (acc 4x2).
// Staging via global_load_lds width=16 into linear LDS (m97 structure).
__global__ __launch_bounds__(256) void gemm_lds(
    const unsigned short* __restrict__ A, const unsigned short* __restrict__ Bw,
    unsigned short* __restrict__ C, int M, int N, int K) {
  __shared__ unsigned short As[128 * 64];
  __shared__ unsigned short Bs[64 * 64];
  int tid = threadIdx.x;
  int lane = tid & 63, w = tid >> 6;
  int wm = (w & 1) * 64, wn = (w >> 1) * 32;
  int row0 = blockIdx.x * 128, col0 = blockIdx.y * 64;
  int lq = lane & 15, g = lane >> 4;
  f32x4 acc[4][2] = {};

  // per-lane global source; each wave-issue fills 8 rows (64 lanes x 16B)
  const unsigned short* Ag =
      A + (size_t)(row0 + w * 8 + (lane >> 3)) * K + (lane & 7) * 8;
  const unsigned short* Bg =
      Bw + (size_t)(col0 + w * 8 + (lane >> 3)) * K + (lane & 7) * 8;

  for (int k0 = 0; k0 < K; k0 += 64) {
    __syncthreads();
#pragma unroll
    for (int it = 0; it < 4; ++it)
      __builtin_amdgcn_global_load_lds(
          (as1_uint*)(Ag + (size_t)(it * 32) * K + k0),
          (as3_uint*)&As[(it * 32 + w * 8) * 64], 16, 0, 0);
#pragma unroll
    for (int it = 0; it < 2; ++it)
      __builtin_amdgcn_global_load_lds(
          (as1_uint*)(Bg + (size_t)(it * 32) * K + k0),
          (as3_uint*)&Bs[(it * 32 + w * 8) * 64], 16, 0, 0);
    __syncthreads();
#pragma unroll
    for (int ks = 0; ks < 2; ++ks) {
      bf16x8 af[4], bfr[2];
#pragma unroll
      for (int i = 0; i < 4; ++i)
        af[i] = *(const bf16x8*)&As[(wm + i * 16 + lq) * 64 + ks * 32 + g * 8];
#pragma unroll
      for (int j = 0; j < 2; ++j)
        bfr[j] = *(const bf16x8*)&Bs[(wn + j * 16 + lq) * 64 + ks * 32 + g * 8];
#pragma unroll
      for (int i = 0; i < 4; ++i)
#pragma unroll
        for (int j = 0; j < 2; ++j)
          acc[i][j] =
              __builtin_amdgcn_mfma_f32_16x16x32_bf16(af[i], bfr[j], acc[i][j], 0, 0, 0);
    }
  }
#pragma unroll
  for (int i = 0; i < 4; ++i)
#pragma unroll
    for (int j = 0; j < 2; ++j)
#pragma unroll
      for (int r = 0; r < 4; ++r)
        C[(size_t)(row0 + wm + i * 16 + g * 4 + r) * N + col0 + wn + j * 16 + lq] =
            f2bf(acc[i][j][r]);
}

// ---------------- per-head projection for q AND k in one dispatch ----------------
// qkb: bf16 [2048][2048] (cols 0-1023 = q, 1024-2047 = k).
// y=0 -> q: write -x0 at d=0 and scale row by 0.125; y=1 -> k.
__global__ __launch_bounds__(256) void proj_both(
    const unsigned short* __restrict__ qkb, unsigned short* __restrict__ qb,
    unsigned short* __restrict__ kb) {
  int tid = threadIdx.x;
  int qmode = (blockIdx.y == 0);
  int g = blockIdx.x * 4 + (tid >> 6);  // row*16 + head
  int lane = tid & 63;
  int row = g >> 4, head = g & 15;
  const unsigned short* src = qkb + (qmode ? 0 : 1024);
  unsigned short* dst = qmode ? qb : kb;
  float t = bf2f(src[(size_t)row * 2048 + head * 64 + lane]);
  float sp = fminf(fmaxf(t, -5.f), 5.f);
  float ssq = (lane == 0) ? 0.f : sp * sp;
#pragma unroll
  for (int o = 32; o; o >>= 1) ssq += __shfl_xor(ssq, o);
  float x0 = sqrtf(1.f + ssq + EPSF);
  float o = (lane == 0) ? (qmode ? -x0 : x0) : sp;
  if (qmode) o *= 0.125f;
  dst[(size_t)row * 1024 + head * 64 + lane] = f2bf(o);
}

// ---------------- MFMA flash attention with async-STAGE (T14) ----------------
__global__ __launch_bounds__(256) void attn_mfma(
    const unsigned short* __restrict__ Qb, const unsigned short* __restrict__ Kb,
    const unsigned short* __restrict__ Vtb, unsigned short* __restrict__ Obf) {
  __shared__ unsigned short Ks[64 * 64];
  __shared__ unsigned short Vs[64 * 64];
  __shared__ unsigned short Ps[4 * 16 * 64];
  int tid = threadIdx.x;
  int lane = tid & 63, w = tid >> 6;
  int g = lane >> 4, lq = lane & 15;
  int bh = blockIdx.x >> 4, qt = blockIdx.x & 15;
  int b = bh >> 4, h = bh & 15;

  const unsigned short* qrow =
      Qb + (size_t)(b * 1024 + qt * 64 + w * 16 + lq) * 1024 + h * 64;
  bf16x8 qf0 = *(const bf16x8*)(qrow + g * 8);
  bf16x8 qf1 = *(const bf16x8*)(qrow + 32 + g * 8);

  float mreg = -1e30f, lreg = 0.f;
  f32x4 acc[4] = {};
  unsigned short* Pw = Ps + w * 16 * 64;
  int sx = 8 * (lq & 7);

  const unsigned short* Ksrc = Kb + (size_t)(b * 1024) * 1024 + h * 64;
  const unsigned short* Vsrc = Vtb + (size_t)(h * 64) * 2048 + b * 1024;

  // staging geometry: thread covers rows sr and sr+32, col-group sc
  int sr = tid >> 3, sc = tid & 7;
  int sw0 = sr * 64 + 8 * (sc ^ (sr & 7));
  int sw1 = (sr + 32) * 64 + 8 * (sc ^ (sr & 7));  // (sr+32)&7 == sr&7
  const unsigned short* Kp = Ksrc + (size_t)sr * 1024 + sc * 8;
  const unsigned short* Vp = Vsrc + (size_t)sr * 2048 + sc * 8;

  uint4 ka0, ka1, vA0, vA1, kb0, kb1, vB0, vB1;
  auto loadA = [&](int kt) {
    ka0 = *(const uint4*)(Kp + (size_t)(kt * 64) * 1024);
    ka1 = *(const uint4*)(Kp + (size_t)(kt * 64 + 32) * 1024);
    vA0 = *(const uint4*)(Vp + kt * 64);
    vA1 = *(const uint4*)(Vp + (size_t)32 * 2048 + kt * 64);
  };
  auto loadB = [&](int kt) {
    kb0 = *(const uint4*)(Kp + (size_t)(kt * 64) * 1024);
    kb1 = *(const uint4*)(Kp + (size_t)(kt * 64 + 32) * 1024);
    vB0 = *(const uint4*)(Vp + kt * 64);
    vB1 = *(const uint4*)(Vp + (size_t)32 * 2048 + kt * 64);
  };
  auto writeLDS = [&](uint4 k0, uint4 k1, uint4 v0, uint4 v1) {
    *(uint4*)&Ks[sw0] = k0; *(uint4*)&Ks[sw1] = k1;
    *(uint4*)&Vs[sw0] = v0; *(uint4*)&Vs[sw1] = v1;
  };
  auto compute = [&]() {
    f32x4 st[4];
#pragma unroll
    for (int i = 0; i < 4; ++i) {
      int ro = i * 16 + lq;
      int rb = ro * 64, xx = 8 * (ro & 7);
      bf16x8 a0 = *(const bf16x8*)&Ks[rb + ((g * 8) ^ xx)];
      bf16x8 a1 = *(const bf16x8*)&Ks[rb + ((32 + g * 8) ^ xx)];
      f32x4 z = {};
      z = __builtin_amdgcn_mfma_f32_16x16x32_bf16(a0, qf0, z, 0, 0, 0);
      st[i] = __builtin_amdgcn_mfma_f32_16x16x32_bf16(a1, qf1, z, 0, 0, 0);
    }
    float pmax = st[0][0];
#pragma unroll
    for (int i = 0; i < 4; ++i)
#pragma unroll
      for (int r = 0; r < 4; ++r) pmax = fmaxf(pmax, st[i][r]);
    pmax = fmaxf(pmax, __shfl_xor(pmax, 16));
    pmax = fmaxf(pmax, __shfl_xor(pmax, 32));
    float nm = fmaxf(mreg, pmax);
    float sc_ = __expf(mreg - nm);
    mreg = nm;
    float ps = 0.f;
#pragma unroll
    for (int i = 0; i < 4; ++i) {
      ushort4 pq;
      float p0 = __expf(st[i][0] - nm);
      float p1 = __expf(st[i][1] - nm);
      float p2 = __expf(st[i][2] - nm);
      float p3 = __expf(st[i][3] - nm);
      ps += (p0 + p1) + (p2 + p3);
      pq.x = f2bf(p0); pq.y = f2bf(p1); pq.z = f2bf(p2); pq.w = f2bf(p3);
      *(ushort4*)&Pw[lq * 64 + ((g * 4 + i * 16) ^ sx)] = pq;
    }
    ps += __shfl_xor(ps, 16);
    ps += __shfl_xor(ps, 32);
    lreg = lreg * sc_ + ps;

    float scr[4];
#pragma unroll
    for (int r = 0; r < 4; ++r) scr[r] = __shfl(sc_, g * 4 + r);
#pragma unroll
    for (int j = 0; j < 4; ++j)
#pragma unroll
      for (int r = 0; r < 4; ++r) acc[j][r] *= scr[r];
#pragma unroll
    for (int ks = 0; ks < 2; ++ks) {
      bf16x8 pa = *(const bf16x8*)&Pw[lq * 64 + ((ks * 32 + g * 8) ^ sx)];
#pragma unroll
      for (int j = 0; j < 4; ++j) {
        int vr = 16 * j + lq;
        bf16x8 vb = *(const bf16x8*)&Vs[vr * 64 + ((ks * 32 + g * 8) ^ sx)];
        acc[j] = __builtin_amdgcn_mfma_f32_16x16x32_bf16(pa, vb, acc[j], 0, 0, 0);
      }
    }
  };

  loadA(0);
  for (int kt = 0; kt < 16; kt += 2) {
    __syncthreads();
    writeLDS(ka0, ka1, vA0, vA1);
    loadB(kt + 1);            // in flight during compute(kt)
    __syncthreads();
    compute();
    __syncthreads();
    writeLDS(kb0, kb1, vB0, vB1);
    if (kt + 2 < 16) loadA(kt + 2);  // in flight during compute(kt+1)
    __syncthreads();
    compute();
  }

  float linv = 1.f / lreg;
  float ilr[4];
#pragma unroll
  for (int r = 0; r < 4; ++r) ilr[r] = __shfl(linv, g * 4 + r);
  unsigned short* obase =
      Obf + (size_t)(b * 1024 + qt * 64 + w * 16) * 1024 + h * 64;
#pragma unroll
  for (int r = 0; r < 4; ++r)
#pragma unroll
    for (int j = 0; j < 4; ++j)
      obase[(size_t)(g * 4 + r) * 1024 + 16 * j + lq] = f2bf(acc[j][r] * ilr[r]);
}

// ---------------- exp_map at origin + project (bf16 in, f32 out) ----------------
__global__ __launch_bounds__(256) void expmap_project(
    const unsigned short* __restrict__ c2, float* __restrict__ out) {
  int row = blockIdx.x;
  int tid = threadIdx.x;
  const unsigned short* cr = c2 + (size_t)row * 1024;
  float vals[4];
  float ssq = 0.f;
#pragma unroll
  for (int i = 0; i < 4; ++i) {
    int c = tid + i * 256;
    float t = bf2f(cr[c]);
    vals[i] = (c == 0) ? 0.f : t;
    ssq += vals[i] * vals[i];
  }
#pragma unroll
  for (int off = 32; off; off >>= 1) ssq += __shfl_xor(ssq, off);
  __shared__ float red1[4], red2[4];
  int wv = tid >> 6;
  if ((tid & 63) == 0) red1[wv] = ssq;
  __syncthreads();
  ssq = red1[0] + red1[1] + red1[2] + red1[3];
  float vn = fminf(sqrtf(ssq + EPSF), 5.f);
  float bf = sinhf(vn) / (vn + EPSF);
  float s2 = 0.f;
#pragma unroll
  for (int i = 0; i < 4; ++i) {
    float r = fminf(fmaxf(bf * vals[i], -8.f), 8.f);
    vals[i] = r;
    s2 += r * r;
  }
#pragma unroll
  for (int off = 32; off; off >>= 1) s2 += __shfl_xor(s2, off);
  if ((tid & 63) == 0) red2[wv] = s2;
  __syncthreads();
  s2 = red2[0] + red2[1] + red2[2] + red2[3];
  float x0 = sqrtf(1.f + s2 + EPSF);
  float* orow = out + (size_t)row * 1024;
#pragma unroll
  for (int i = 0; i < 4; ++i) {
    int c = tid + i * 256;
    orow[c] = (c == 0) ? x0 : vals[i];
  }
}

extern "C" void kernel_launch(void* const* d_in, const int* in_sizes, int n_in,
                              void* d_out, int out_size, void* d_ws, size_t ws_size,
                              hipStream_t stream) {
  (void)in_sizes; (void)n_in; (void)out_size; (void)ws_size;
  const float* x  = (const float*)d_in[0];
  const float* Wq = (const float*)d_in[1];
  const float* Wk = (const float*)d_in[2];
  const float* Wv = (const float*)d_in[3];
  const float* Wo = (const float*)d_in[4];
  float* out = (float*)d_out;

  char* w = (char*)d_ws;
  unsigned short* vbf = (unsigned short*)w; w += (size_t)2048 * 1024 * 2;
  unsigned short* wqk = (unsigned short*)w; w += (size_t)2048 * 1024 * 2;
  unsigned short* wvb = (unsigned short*)w; w += (size_t)1024 * 1024 * 2;
  unsigned short* wob = (unsigned short*)w; w += (size_t)1024 * 1024 * 2;
  unsigned short* qkb = (unsigned short*)w; w += (size_t)2048 * 2048 * 2;
  unsigned short* vtb = (unsigned short*)w; w += (size_t)1024 * 2048 * 2;
  unsigned short* qb  = (unsigned short*)w; w += (size_t)2048 * 1024 * 2;
  unsigned short* kb  = (unsigned short*)w; w += (size_t)2048 * 1024 * 2;
  unsigned short* aob = (unsigned short*)w; w += (size_t)2048 * 1024 * 2;
  unsigned short* c2  = (unsigned short*)w; w += (size_t)2048 * 1024 * 2;

  prep_logmap<<<2048, 256, 0, stream>>>(x, vbf);
  conv_weights<<<dim3(1024, 4), 256, 0, stream>>>(Wq, Wk, Wv, Wo, wqk, wvb, wob);

  // fused Q|K GEMM: [2048,1024] @ [2048,1024]^T -> [2048][2048]
  gemm_lds<<<dim3(16, 32), 256, 0, stream>>>(vbf, wqk, qkb, 2048, 2048, 1024);
  // V^T: Wv [1024,1024] @ v^T -> [1024][2048]
  gemm_lds<<<dim3(8, 32), 256, 0, stream>>>(wvb, vbf, vtb, 1024, 2048, 1024);

  proj_both<<<dim3(8192, 2), 256, 0, stream>>>(qkb, qb, kb);

  attn_mfma<<<512, 256, 0, stream>>>(qb, kb, vtb, aob);

  gemm_lds<<<dim3(16, 16), 256, 0, stream>>>(aob, wob, c2, 2048, 1024, 1024);
  expmap_project<<<2048, 256, 0, stream>>>(c2, out);
}